// Round 13
// baseline (678.291 us; speedup 1.0000x reference)
//
#include <hip/hip_runtime.h>
#include <hip/hip_bf16.h>

typedef __hip_bfloat16 bf16;

// Problem constants
#define BB    4
#define LQ    4096
#define LIN   16464
#define DM    768
#define NH    12
#define HD    64
#define K_DIM 768
// Levels: (112,112),(56,56),(28,28); starts 0,12544,15680; query grid 64x64

typedef __attribute__((ext_vector_type(8))) __bf16 bfrag;
typedef __attribute__((ext_vector_type(4))) float  ffrag;

// ---------------------------------------------------------------------------
// async global->LDS 16B per lane (LDS dest is wave-uniform base + lane*16)
// ---------------------------------------------------------------------------
__device__ __forceinline__ void g2l16(const void* g, void* l) {
    __builtin_amdgcn_global_load_lds(
        (const __attribute__((address_space(1))) void*)g,
        (__attribute__((address_space(3))) void*)l, 16, 0, 0);
}

// bijective XCD-chunk swizzle (m204)
__device__ __forceinline__ int xcd_swz(int orig, int nwg) {
    int xcd = orig & 7, within = orig >> 3;
    int q = nwg >> 3, r = nwg & 7;
    return (xcd < r ? xcd * (q + 1) : r * (q + 1) + (xcd - r) * q) + within;
}

// ---------------------------------------------------------------------------
// LayerNorm over last dim 768: one wave per row, 4 rows/block.
// ---------------------------------------------------------------------------
__global__ __launch_bounds__(256) void ln_kernel(
    const float* __restrict__ x, const float* __restrict__ g,
    const float* __restrict__ beta, bf16* __restrict__ y)
{
    int r = blockIdx.x * 4 + (threadIdx.x >> 6);
    int lane = threadIdx.x & 63;
    const float4* xr = (const float4*)(x + (size_t)r * DM);
    float4 v[3];
    #pragma unroll
    for (int i = 0; i < 3; i++) v[i] = xr[lane + 64 * i];
    float s = 0.f, ss = 0.f;
    #pragma unroll
    for (int i = 0; i < 3; i++) {
        s  += v[i].x + v[i].y + v[i].z + v[i].w;
        ss += v[i].x * v[i].x + v[i].y * v[i].y + v[i].z * v[i].z + v[i].w * v[i].w;
    }
    #pragma unroll
    for (int m = 1; m <= 32; m <<= 1) {
        s  += __shfl_xor(s, m);
        ss += __shfl_xor(ss, m);
    }
    float mean = s * (1.f / DM);
    float inv  = rsqrtf(ss * (1.f / DM) - mean * mean + 1e-6f);
    bf16* yr = y + (size_t)r * DM;
    #pragma unroll
    for (int i = 0; i < 3; i++) {
        float4 gg = ((const float4*)g)[lane + 64 * i];
        float4 bb = ((const float4*)beta)[lane + 64 * i];
        union { bf16 h[4]; uint2 u; } p;
        p.h[0] = __float2bfloat16((v[i].x - mean) * inv * gg.x + bb.x);
        p.h[1] = __float2bfloat16((v[i].y - mean) * inv * gg.y + bb.y);
        p.h[2] = __float2bfloat16((v[i].z - mean) * inv * gg.z + bb.z);
        p.h[3] = __float2bfloat16((v[i].w - mean) * inv * gg.w + bb.w);
        *(uint2*)(yr + (lane + 64 * i) * 4) = p.u;
    }
}

// ---------------------------------------------------------------------------
// Cast + transpose weights: W (768 x N f32, row-major) -> Wt (gridX*32 x 768 bf16)
// ---------------------------------------------------------------------------
__global__ __launch_bounds__(256) void cast_transpose(
    const float* __restrict__ W, bf16* __restrict__ Wt, int N)
{
    __shared__ float t[32][33];
    int n0 = blockIdx.x * 32, k0 = blockIdx.y * 32;
    int tx = threadIdx.x & 31, ty = threadIdx.x >> 5;  // ty 0..7
    #pragma unroll
    for (int i = 0; i < 4; i++) {
        int k = k0 + ty + i * 8;
        int n = n0 + tx;
        t[ty + i * 8][tx] = (n < N) ? W[(size_t)k * N + n] : 0.f;
    }
    __syncthreads();
    #pragma unroll
    for (int i = 0; i < 4; i++) {
        int n = n0 + ty + i * 8;
        Wt[(size_t)n * K_DIM + k0 + tx] = __float2bfloat16(t[tx][ty + i * 8]);
    }
}

// ---------------------------------------------------------------------------
// Value GEMM, R13: 256x128 tile, 8 waves, per-wave 128x32 (acc[8][2] = 64
// regs; __launch_bounds__(512,4) caps waves at <=128 VGPR -> 4 waves/SIMD ->
// 2 blocks/CU). R11/R12's 256x256 shape needed ~248 unified regs (acc 128) ->
// hard 1 block/CU, no cross-block overlap, 4-round makespan quantization.
// 3-deep LDS rotation (3 x 24KB = 72KB; 2 blocks = 144KB <= 160), counted
// vmcnt(6): 2 K-tiles (6 loads) in flight across barriers (R11-proven form).
// ---------------------------------------------------------------------------
__global__ __launch_bounds__(512, 4) void gemm_value(
    const bf16*  __restrict__ A,
    const bf16*  __restrict__ Bt,
    const float* __restrict__ bias,
    bf16*        __restrict__ C,
    int M, int N)
{
    __shared__ __align__(16) char lds[73728];   // 3 x (A 16K + B 8K)

    int tid  = threadIdx.x;
    int lane = tid & 63;
    int wave = tid >> 6;

    int nwg  = gridDim.x * gridDim.y;
    int orig = blockIdx.y * gridDim.x + blockIdx.x;
    int wg   = xcd_swz(orig, nwg);
    int bn = (wg % gridDim.x) * 128;
    int bm = (wg / gridDim.x) * 256;

    int ahalf = wave >> 2;            // rows [ahalf*128, +128)
    int wc    = (wave & 3) * 32;      // cols [wc, +32)

    int mrow = lane & 15;
    int kqs  = (((lane >> 4) ^ ((mrow >> 1) & 3)) * 8);  // swizzled k-octet

    ffrag acc[8][2] = {};

    // staging: A [256][32] = 16KB (2 chunks/thread), B [128][32] = 8KB (1).
    int rA = tid >> 2;                          // 0..127
    int kb = (((tid & 3) ^ ((rA >> 1) & 3)) * 8);
    int ra0 = min(bm + rA, M - 1), ra1 = min(bm + 128 + rA, M - 1);
    const bf16* gA0 = A  + (size_t)ra0 * K_DIM + kb;
    const bf16* gA1 = A  + (size_t)ra1 * K_DIM + kb;
    const bf16* gB0 = Bt + (size_t)(bn + rA) * K_DIM + kb;   // N=768 exact

    auto stage = [&](char* buf, int kt) {
        const int ko = kt * 32;
        g2l16(gA0 + ko, buf + tid * 16);
        g2l16(gA1 + ko, buf + tid * 16 + 8192);
        g2l16(gB0 + ko, buf + 16384 + tid * 16);
    };

    char* b0 = lds;
    char* b1 = lds + 24576;
    char* b2 = lds + 49152;
    stage(b0, 0); stage(b1, 1); stage(b2, 2);   // 9 loads in flight

    #pragma unroll
    for (int kt = 0; kt < 24; kt++) {
        if (kt + 2 < 24)      asm volatile("s_waitcnt vmcnt(6)" ::: "memory");
        else if (kt + 1 < 24) asm volatile("s_waitcnt vmcnt(3)" ::: "memory");
        else                  asm volatile("s_waitcnt vmcnt(0)" ::: "memory");
        __builtin_amdgcn_s_barrier();

        const char* Ab = b0 + (ahalf * 128) * 64;
        const char* Bb = b0 + 16384 + wc * 64;
        bfrag af[8], bf[2];
        #pragma unroll
        for (int mr = 0; mr < 8; mr++)
            af[mr] = *(const bfrag*)(Ab + (mr * 16 + mrow) * 64 + kqs * 2);
        #pragma unroll
        for (int nc = 0; nc < 2; nc++)
            bf[nc] = *(const bfrag*)(Bb + (nc * 16 + mrow) * 64 + kqs * 2);

        __builtin_amdgcn_s_setprio(1);
        #pragma unroll
        for (int mr = 0; mr < 8; mr++)
            #pragma unroll
            for (int nc = 0; nc < 2; nc++)
                acc[mr][nc] = __builtin_amdgcn_mfma_f32_16x16x32_bf16(
                    af[mr], bf[nc], acc[mr][nc], 0, 0, 0);
        __builtin_amdgcn_s_setprio(0);

        __builtin_amdgcn_s_barrier();       // all waves done reading b0
        if (kt + 3 < 24) stage(b0, kt + 3); // refill freed buffer
        char* tp = b0; b0 = b1; b1 = b2; b2 = tp;
    }

    // epilogue: C/D layout col = lane&15, row = (lane>>4)*4 + reg
    int q4 = (lane >> 4) * 4;
    #pragma unroll
    for (int mr = 0; mr < 8; mr++) {
        #pragma unroll
        for (int rr = 0; rr < 4; rr++) {
            int rg = bm + ahalf * 128 + mr * 16 + q4 + rr;
            if (rg < M) {
                #pragma unroll
                for (int nc = 0; nc < 2; nc++) {
                    int cg = bn + wc + nc * 16 + mrow;
                    C[(size_t)rg * N + cg] =
                        __float2bfloat16(acc[mr][nc][rr] + bias[cg]);
                }
            }
        }
    }
}

// ---------------------------------------------------------------------------
// 128x128 2-phase GEMM body (R5-verified), for comb/out GEMMs.
// ---------------------------------------------------------------------------
__device__ __forceinline__ void gemm128_body(
    const bf16*  __restrict__ A,
    const bf16*  __restrict__ Bt,
    const float* __restrict__ bias,
    void*        __restrict__ C,
    const float* __restrict__ resid,
    const float* __restrict__ gamma,
    const float* __restrict__ bias2,
    int M, int N, int mode, int nsplit, char* lds)
{
    int tid  = threadIdx.x;
    int lane = tid & 63;

    int nwg  = gridDim.x * gridDim.y;
    int orig = blockIdx.y * gridDim.x + blockIdx.x;
    int wg = xcd_swz(orig, nwg);
    int bn = (wg % gridDim.x) * 128;
    int bm = (wg / gridDim.x) * 128;

    int wave = tid >> 6;
    int wr = (wave & 1) * 64, wc = (wave >> 1) * 64;

    ffrag acc[4][4] = {};

    int rA = tid >> 2;                       // 0..63
    int kb = (((tid & 3) ^ ((rA >> 1) & 3)) * 8);
    int ra0 = min(bm + rA, M - 1), ra1 = min(bm + 64 + rA, M - 1);
    const bf16* gA0 = A  + (size_t)ra0 * K_DIM + kb;
    const bf16* gA1 = A  + (size_t)ra1 * K_DIM + kb;
    const bf16* gB0 = Bt + (size_t)(bn + rA) * K_DIM + kb;
    const bf16* gB1 = Bt + (size_t)(bn + 64 + rA) * K_DIM + kb;

    int mrow = lane & 15;
    int kqs  = (((lane >> 4) ^ ((mrow >> 1) & 3)) * 8);

    auto stage = [&](char* buf, int kt) {
        const int ko = kt * 32;
        g2l16(gA0 + ko, buf + tid * 16);
        g2l16(gA1 + ko, buf + tid * 16 + 4096);
        g2l16(gB0 + ko, buf + 8192 + tid * 16);
        g2l16(gB1 + ko, buf + 8192 + tid * 16 + 4096);
    };

    stage(lds, 0);
    asm volatile("s_waitcnt vmcnt(0)" ::: "memory");
    __builtin_amdgcn_s_barrier();

    #pragma unroll
    for (int kt = 0; kt < 24; kt++) {
        char* cur = lds + (kt & 1) * 16384;
        char* nxt = lds + ((kt & 1) ^ 1) * 16384;
        if (kt + 1 < 24) stage(nxt, kt + 1);

        bfrag a[4], b[4];
        #pragma unroll
        for (int t = 0; t < 4; t++) {
            a[t] = *(const bfrag*)(cur + ((wr + t * 16 + mrow) * 32 + kqs) * 2);
            b[t] = *(const bfrag*)(cur + 8192 + ((wc + t * 16 + mrow) * 32 + kqs) * 2);
        }
        __builtin_amdgcn_s_setprio(1);
        #pragma unroll
        for (int i = 0; i < 4; i++)
            #pragma unroll
            for (int j = 0; j < 4; j++)
                acc[i][j] = __builtin_amdgcn_mfma_f32_16x16x32_bf16(
                    a[i], b[j], acc[i][j], 0, 0, 0);
        __builtin_amdgcn_s_setprio(0);

        asm volatile("s_waitcnt vmcnt(0)" ::: "memory");
        __builtin_amdgcn_s_barrier();
    }

    int q4 = (lane >> 4) * 4;
    #pragma unroll
    for (int i = 0; i < 4; i++) {
        #pragma unroll
        for (int rr = 0; rr < 4; rr++) {
            int rg = bm + wr + i * 16 + q4 + rr;
            if (rg < M) {
                #pragma unroll
                for (int j = 0; j < 4; j++) {
                    int cg = bn + wc + j * 16 + mrow;
                    if (cg < N) {
                        float bv = (mode == 3 && cg >= nsplit) ? bias2[cg - nsplit]
                                                               : bias[cg];
                        float v = acc[i][j][rr] + bv;
                        size_t idx = (size_t)rg * N + cg;
                        if (mode == 2)      ((float*)C)[idx] = resid[idx] + gamma[cg] * v;
                        else                ((float*)C)[idx] = v;
                    }
                }
            }
        }
    }
}

__global__ __launch_bounds__(256) void gemm128_comb(
    const bf16* __restrict__ A, const bf16* __restrict__ Bt,
    const float* __restrict__ bias, void* __restrict__ C,
    const float* __restrict__ bias2, int M, int N, int nsplit)
{
    __shared__ __align__(16) char lds[32768];
    gemm128_body(A, Bt, bias, C, nullptr, nullptr, bias2, M, N, 3, nsplit, lds);
}

__global__ __launch_bounds__(256) void gemm128_out(
    const bf16* __restrict__ A, const bf16* __restrict__ Bt,
    const float* __restrict__ bias, void* __restrict__ C,
    const float* __restrict__ resid, const float* __restrict__ gamma,
    int M, int N)
{
    __shared__ __align__(16) char lds[32768];
    gemm128_body(A, Bt, bias, C, resid, gamma, nullptr, M, N, 2, 0, lds);
}

// ---------------------------------------------------------------------------
// Sampling prep (R12-verified): per-corner records {idx, w}.
// ---------------------------------------------------------------------------
__global__ __launch_bounds__(256) void prep_kernel(
    const float* __restrict__ comb, uint4* __restrict__ pre)
{
    int t  = blockIdx.x * 256 + threadIdx.x;   // (bq*NH + h)*12 + p
    int p  = t % 12;
    int uh = t / 12;
    int h  = uh % NH;
    int bq = uh / NH;
    int q  = bq & (LQ - 1);
    int b  = bq >> 12;

    const float* rowp = comb + (size_t)bq * 432;
    const float* lg = rowp + 288 + h * 12;

    float4 a4 = ((const float4*)lg)[0];
    float4 b4 = ((const float4*)lg)[1];
    float4 c4 = ((const float4*)lg)[2];
    float mx = fmaxf(fmaxf(fmaxf(fmaxf(a4.x, a4.y), fmaxf(a4.z, a4.w)),
                           fmaxf(fmaxf(b4.x, b4.y), fmaxf(b4.z, b4.w))),
                     fmaxf(fmaxf(c4.x, c4.y), fmaxf(c4.z, c4.w)));
    float den = __expf(a4.x - mx) + __expf(a4.y - mx) + __expf(a4.z - mx) +
                __expf(a4.w - mx) + __expf(b4.x - mx) + __expf(b4.y - mx) +
                __expf(b4.z - mx) + __expf(b4.w - mx) + __expf(c4.x - mx) +
                __expf(c4.y - mx) + __expf(c4.z - mx) + __expf(c4.w - mx);
    float lp  = lg[p];
    float awn = __expf(lp - mx) / den;        // normalized attention weight

    int lvl = p >> 2;
    const int wl = (lvl == 0) ? 112 : (lvl == 1 ? 56 : 28);
    const int sl = (lvl == 0) ? 0   : (lvl == 1 ? 12544 : 15680);

    float2 oxy = *(const float2*)(rowp + h * 24 + p * 2);

    float rx = ((q & 63) + 0.5f) * (1.f / 64.f);
    float ry = ((q >> 6) + 0.5f) * (1.f / 64.f);
    float x = rx * wl + oxy.x - 0.5f;
    float y = ry * wl + oxy.y - 0.5f;
    float xf = floorf(x), yf = floorf(y);
    float wx = x - xf, wy = y - yf;
    int x0 = (int)xf, x1 = x0 + 1;
    int y0 = (int)yf, y1 = y0 + 1;
    bool vx0 = (unsigned)x0 < (unsigned)wl, vx1 = (unsigned)x1 < (unsigned)wl;
    bool vy0 = (unsigned)y0 < (unsigned)wl, vy1 = (unsigned)y1 < (unsigned)wl;
    int x0c = min(max(x0, 0), wl - 1), x1c = min(max(x1, 0), wl - 1);
    int y0c = min(max(y0, 0), wl - 1), y1c = min(max(y1, 0), wl - 1);

    int base = b * LIN + sl;
    int yb0 = (base + y0c * wl) * (NH * HD) + h * HD;
    int yb1 = (base + y1c * wl) * (NH * HD) + h * HD;
    int xb0 = x0c * (NH * HD);
    int xb1 = x1c * (NH * HD);

    float wx0 = vx0 ? (1.f - wx) * awn : 0.f;
    float wx1 = vx1 ? wx * awn : 0.f;
    float wy0f = vy0 ? (1.f - wy) : 0.f;
    float wy1f = vy1 ? wy : 0.f;

    uint4 r0 = {(unsigned)(yb0 + xb0), __float_as_uint(wx0 * wy0f),
                (unsigned)(yb0 + xb1), __float_as_uint(wx1 * wy0f)};
    uint4 r1 = {(unsigned)(yb1 + xb0), __float_as_uint(wx0 * wy1f),
                (unsigned)(yb1 + xb1), __float_as_uint(wx1 * wy1f)};
    pre[(size_t)t * 2 + 0] = r0;
    pre[(size_t)t * 2 + 1] = r1;
}

// ---------------------------------------------------------------------------
// Deformable sampling (R12-verified): 3-phase batched loads, per-corner recs.
// ---------------------------------------------------------------------------
__global__ __launch_bounds__(256) void sample_kernel(
    const bf16*  __restrict__ value,
    const uint4* __restrict__ pre,
    bf16*        __restrict__ attn)
{
    __shared__ float red[4][8][64];   // [wave][slot][ch] = 8 KB

    int wv   = threadIdx.x >> 6;
    int wg   = xcd_swz(blockIdx.x, gridDim.x);
    int unit = __builtin_amdgcn_readfirstlane((wg << 2) + wv);
    int lane = threadIdx.x & 63;
    int o   = lane & 7;          // channel octet
    int c8  = lane >> 3;         // corner slot 0..7
    int k   = c8 & 3;            // corner dy*2+dx
    int hi  = (c8 >> 2) & 1;     // which point of the pair
    int h  = unit % NH;
    int bq = unit / NH;

    const uint2* pr = (const uint2*)((const char*)pre
        + (size_t)unit * 384 + hi * 32 + k * 8);

    uint2 rec[6];
    #pragma unroll
    for (int it = 0; it < 6; it++) rec[it] = pr[it * 8];

    const bf16* vb = value + o * 8;
    uint4 v[6];
    #pragma unroll
    for (int it = 0; it < 6; it++)
        v[it] = *(const uint4*)(vb + (int)rec[it].x);

    float acc[8] = {0.f};
    #pragma unroll
    for (int it = 0; it < 6; it++) {
        float w = __uint_as_float(rec[it].y);
        const unsigned* u = (const unsigned*)&v[it];
        #pragma unroll
        for (int j = 0; j < 4; j++) {
            float f0 = __uint_as_float(u[j] << 16);
            float f1 = __uint_as_float(u[j] & 0xFFFF0000u);
            acc[j * 2 + 0] = fmaf(w, f0, acc[j * 2 + 0]);
            acc[j * 2 + 1] = fmaf(w, f1, acc[j * 2 + 1]);
        }
    }

    {
        float* rw = &red[wv][c8][0];
        int base = (o * 8 + c8 * 4) & 63;          // multiple of 4
        *(float4*)&rw[base] = float4{acc[0], acc[1], acc[2], acc[3]};
        *(float4*)&rw[(base + 4) & 63] = float4{acc[4], acc[5], acc[6], acc[7]};
    }
    asm volatile("s_waitcnt lgkmcnt(0)" ::: "memory");
    __builtin_amdgcn_sched_barrier(0);
    float sum = 0.f;
    #pragma unroll
    for (int s = 0; s < 8; s++)
        sum += red[wv][s][(lane + s * 4) & 63];

    attn[(size_t)bq * DM + h * HD + lane] = __float2bfloat16(sum);
}

// ---------------------------------------------------------------------------
extern "C" void kernel_launch(void* const* d_in, const int* in_sizes, int n_in,
                              void* d_out, int out_size, void* d_ws, size_t ws_size,
                              hipStream_t stream)
{
    const float* query  = (const float*)d_in[0];
    const float* feat   = (const float*)d_in[1];
    const float* ln_q_g = (const float*)d_in[2];
    const float* ln_q_b = (const float*)d_in[3];
    const float* ln_f_g = (const float*)d_in[4];
    const float* ln_f_b = (const float*)d_in[5];
    const float* W_off  = (const float*)d_in[6];
    const float* b_off  = (const float*)d_in[7];
    const float* W_attn = (const float*)d_in[8];
    const float* b_attn = (const float*)d_in[9];
    const float* W_val  = (const float*)d_in[10];
    const float* b_val  = (const float*)d_in[11];
    const float* W_out  = (const float*)d_in[12];
    const float* b_out  = (const float*)d_in[13];
    const float* gamma  = (const float*)d_in[14];
    float* out = (float*)d_out;

    char* ws = (char*)d_ws;
    char* od = (char*)d_out;
    const int M_F = BB * LIN;   // 65856
    const int M_Q = BB * LQ;    // 16384

    // ws layout (227,475,456 B proven):
    bf16*  value  = (bf16*)(ws);
    bf16*  f_ln   = (bf16*)(ws + 101154816);
    bf16*  Wt_out = (bf16*)(ws + 101154816);
    // pre lives in the dead f_ln region, after Wt_out (1.2 MB): 75.5 MB fits
    uint4* pre    = (uint4*)(ws + 101154816 + 4194304);
    bf16*  q_ln   = (bf16*)(ws + 202309632);
    bf16*  attn   = (bf16*)(ws + 202309632);

    // d_out as scratch (dead before final GEMM):
    bf16*  Wt_val  = (bf16*)(od);
    bf16*  Wt_comb = (bf16*)(od + 1179648);
    float* comb    = (float*)(od + 2162688);

    // 1. weight cast/transpose
    cast_transpose<<<dim3(24, 24), 256, 0, stream>>>(W_val, Wt_val, 768);
    cast_transpose<<<dim3(9, 24), 256, 0, stream>>>(W_off, Wt_comb, 288);
    cast_transpose<<<dim3(7, 24), 256, 0, stream>>>(
        W_attn, Wt_comb + (size_t)288 * K_DIM, 144);

    // 2. LayerNorms (wave-per-row; rows are multiples of 4)
    ln_kernel<<<M_F / 4, 256, 0, stream>>>(feat, ln_f_g, ln_f_b, f_ln);
    ln_kernel<<<M_Q / 4, 256, 0, stream>>>(query, ln_q_g, ln_q_b, q_ln);

    // 3. value = f_ln @ W_val + b_val (bf16) — 256x128, 2 blocks/CU
    gemm_value<<<dim3(6, (M_F + 255) / 256), 512, 0, stream>>>(
        f_ln, Wt_val, b_val, value, M_F, DM);

    // 4. Wt_out into f_ln's (now dead) region
    cast_transpose<<<dim3(24, 24), 256, 0, stream>>>(W_out, Wt_out, 768);

    // 5. comb = q_ln @ [W_off | W_attn] + [b_off | b_attn] (f32, N=432)
    gemm128_comb<<<dim3(4, M_Q / 128), 256, 0, stream>>>(
        q_ln, Wt_comb, b_off, comb, b_attn, M_Q, 432, 288);

    // 5.5 per-point sampling precompute (softmax + addressing, once per point)
    prep_kernel<<<(M_Q * NH * 12) / 256, 256, 0, stream>>>(comb, pre);

    // 6. deformable sampling -> attn (bf16)
    sample_kernel<<<(M_Q * NH) / 4, 256, 0, stream>>>(value, pre, attn);

    // 7. out = query + gamma * (attn @ W_out + b_out)
    gemm128_out<<<dim3(6, M_Q / 128), 256, 0, stream>>>(
        attn, Wt_out, b_out, out, query, gamma, M_Q, DM);
}

// Round 14
// 663.583 us; speedup vs baseline: 1.0222x; 1.0222x over previous
//
#include <hip/hip_runtime.h>
#include <hip/hip_bf16.h>

typedef __hip_bfloat16 bf16;

// Problem constants
#define BB    4
#define LQ    4096
#define LIN   16464
#define DM    768
#define NH    12
#define HD    64
#define K_DIM 768
// Levels: (112,112),(56,56),(28,28); starts 0,12544,15680; query grid 64x64

typedef __attribute__((ext_vector_type(8))) __bf16 bfrag;
typedef __attribute__((ext_vector_type(4))) float  ffrag;

// ---------------------------------------------------------------------------
// async global->LDS 16B per lane (LDS dest is wave-uniform base + lane*16)
// ---------------------------------------------------------------------------
__device__ __forceinline__ void g2l16(const void* g, void* l) {
    __builtin_amdgcn_global_load_lds(
        (const __attribute__((address_space(1))) void*)g,
        (__attribute__((address_space(3))) void*)l, 16, 0, 0);
}

// bijective XCD-chunk swizzle (m204)
__device__ __forceinline__ int xcd_swz(int orig, int nwg) {
    int xcd = orig & 7, within = orig >> 3;
    int q = nwg >> 3, r = nwg & 7;
    return (xcd < r ? xcd * (q + 1) : r * (q + 1) + (xcd - r) * q) + within;
}

// ---------------------------------------------------------------------------
// LayerNorm over last dim 768: one wave per row, 4 rows/block.
// ---------------------------------------------------------------------------
__global__ __launch_bounds__(256) void ln_kernel(
    const float* __restrict__ x, const float* __restrict__ g,
    const float* __restrict__ beta, bf16* __restrict__ y)
{
    int r = blockIdx.x * 4 + (threadIdx.x >> 6);
    int lane = threadIdx.x & 63;
    const float4* xr = (const float4*)(x + (size_t)r * DM);
    float4 v[3];
    #pragma unroll
    for (int i = 0; i < 3; i++) v[i] = xr[lane + 64 * i];
    float s = 0.f, ss = 0.f;
    #pragma unroll
    for (int i = 0; i < 3; i++) {
        s  += v[i].x + v[i].y + v[i].z + v[i].w;
        ss += v[i].x * v[i].x + v[i].y * v[i].y + v[i].z * v[i].z + v[i].w * v[i].w;
    }
    #pragma unroll
    for (int m = 1; m <= 32; m <<= 1) {
        s  += __shfl_xor(s, m);
        ss += __shfl_xor(ss, m);
    }
    float mean = s * (1.f / DM);
    float inv  = rsqrtf(ss * (1.f / DM) - mean * mean + 1e-6f);
    bf16* yr = y + (size_t)r * DM;
    #pragma unroll
    for (int i = 0; i < 3; i++) {
        float4 gg = ((const float4*)g)[lane + 64 * i];
        float4 bb = ((const float4*)beta)[lane + 64 * i];
        union { bf16 h[4]; uint2 u; } p;
        p.h[0] = __float2bfloat16((v[i].x - mean) * inv * gg.x + bb.x);
        p.h[1] = __float2bfloat16((v[i].y - mean) * inv * gg.y + bb.y);
        p.h[2] = __float2bfloat16((v[i].z - mean) * inv * gg.z + bb.z);
        p.h[3] = __float2bfloat16((v[i].w - mean) * inv * gg.w + bb.w);
        *(uint2*)(yr + (lane + 64 * i) * 4) = p.u;
    }
}

// ---------------------------------------------------------------------------
// Cast + transpose weights: W (768 x N f32, row-major) -> Wt (gridX*32 x 768 bf16)
// ---------------------------------------------------------------------------
__global__ __launch_bounds__(256) void cast_transpose(
    const float* __restrict__ W, bf16* __restrict__ Wt, int N)
{
    __shared__ float t[32][33];
    int n0 = blockIdx.x * 32, k0 = blockIdx.y * 32;
    int tx = threadIdx.x & 31, ty = threadIdx.x >> 5;  // ty 0..7
    #pragma unroll
    for (int i = 0; i < 4; i++) {
        int k = k0 + ty + i * 8;
        int n = n0 + tx;
        t[ty + i * 8][tx] = (n < N) ? W[(size_t)k * N + n] : 0.f;
    }
    __syncthreads();
    #pragma unroll
    for (int i = 0; i < 4; i++) {
        int n = n0 + ty + i * 8;
        Wt[(size_t)n * K_DIM + k0 + tx] = __float2bfloat16(t[tx][ty + i * 8]);
    }
}

// ---------------------------------------------------------------------------
// 256x128-tile 8-wave GEMM pipe (R13-verified structure), MODE-templated
// epilogue. BK=32, 3-deep LDS rotation (72KB; 2 blocks/CU via
// __launch_bounds__(512,4) -> <=128 unified regs/wave), counted vmcnt(6).
// MODE 0: bf16 store (value). MODE 2: f32 = resid + gamma*(acc+bias) (out).
// MODE 3: f32 dual-bias split at nsplit, store guard cg < N_out (comb;
// B matrix is zero-padded to N_mat rows so staging needs no guards).
// ---------------------------------------------------------------------------
template<int MODE>
__global__ __launch_bounds__(512, 4) void gemm_pipe(
    const bf16*  __restrict__ A,
    const bf16*  __restrict__ Bt,
    const float* __restrict__ bias,
    void*        __restrict__ C,
    const float* __restrict__ resid,
    const float* __restrict__ gamma,
    const float* __restrict__ bias2,
    int M, int N_out, int nsplit)
{
    __shared__ __align__(16) char lds[73728];   // 3 x (A 16K + B 8K)

    int tid  = threadIdx.x;
    int lane = tid & 63;
    int wave = tid >> 6;

    int nwg  = gridDim.x * gridDim.y;
    int orig = blockIdx.y * gridDim.x + blockIdx.x;
    int wg   = xcd_swz(orig, nwg);
    int bn = (wg % gridDim.x) * 128;
    int bm = (wg / gridDim.x) * 256;

    int ahalf = wave >> 2;            // rows [ahalf*128, +128)
    int wc    = (wave & 3) * 32;      // cols [wc, +32)

    int mrow = lane & 15;
    int kqs  = (((lane >> 4) ^ ((mrow >> 1) & 3)) * 8);  // swizzled k-octet

    ffrag acc[8][2] = {};

    // staging: A [256][32] = 16KB (2 chunks/thread), B [128][32] = 8KB (1).
    int rA = tid >> 2;                          // 0..127
    int kb = (((tid & 3) ^ ((rA >> 1) & 3)) * 8);
    int ra0 = min(bm + rA, M - 1), ra1 = min(bm + 128 + rA, M - 1);
    const bf16* gA0 = A  + (size_t)ra0 * K_DIM + kb;
    const bf16* gA1 = A  + (size_t)ra1 * K_DIM + kb;
    const bf16* gB0 = Bt + (size_t)(bn + rA) * K_DIM + kb;   // rows zero-padded

    auto stage = [&](char* buf, int kt) {
        const int ko = kt * 32;
        g2l16(gA0 + ko, buf + tid * 16);
        g2l16(gA1 + ko, buf + tid * 16 + 8192);
        g2l16(gB0 + ko, buf + 16384 + tid * 16);
    };

    char* b0 = lds;
    char* b1 = lds + 24576;
    char* b2 = lds + 49152;
    stage(b0, 0); stage(b1, 1); stage(b2, 2);   // 9 loads in flight

    #pragma unroll
    for (int kt = 0; kt < 24; kt++) {
        if (kt + 2 < 24)      asm volatile("s_waitcnt vmcnt(6)" ::: "memory");
        else if (kt + 1 < 24) asm volatile("s_waitcnt vmcnt(3)" ::: "memory");
        else                  asm volatile("s_waitcnt vmcnt(0)" ::: "memory");
        __builtin_amdgcn_s_barrier();

        const char* Ab = b0 + (ahalf * 128) * 64;
        const char* Bb = b0 + 16384 + wc * 64;
        bfrag af[8], bf[2];
        #pragma unroll
        for (int mr = 0; mr < 8; mr++)
            af[mr] = *(const bfrag*)(Ab + (mr * 16 + mrow) * 64 + kqs * 2);
        #pragma unroll
        for (int nc = 0; nc < 2; nc++)
            bf[nc] = *(const bfrag*)(Bb + (nc * 16 + mrow) * 64 + kqs * 2);

        __builtin_amdgcn_s_setprio(1);
        #pragma unroll
        for (int mr = 0; mr < 8; mr++)
            #pragma unroll
            for (int nc = 0; nc < 2; nc++)
                acc[mr][nc] = __builtin_amdgcn_mfma_f32_16x16x32_bf16(
                    af[mr], bf[nc], acc[mr][nc], 0, 0, 0);
        __builtin_amdgcn_s_setprio(0);

        __builtin_amdgcn_s_barrier();       // all waves done reading b0
        if (kt + 3 < 24) stage(b0, kt + 3); // refill freed buffer
        char* tp = b0; b0 = b1; b1 = b2; b2 = tp;
    }

    // epilogue: C/D layout col = lane&15, row = (lane>>4)*4 + reg
    int q4 = (lane >> 4) * 4;
    #pragma unroll
    for (int mr = 0; mr < 8; mr++) {
        #pragma unroll
        for (int rr = 0; rr < 4; rr++) {
            int rg = bm + ahalf * 128 + mr * 16 + q4 + rr;
            if (rg < M) {
                #pragma unroll
                for (int nc = 0; nc < 2; nc++) {
                    int cg = bn + wc + nc * 16 + mrow;
                    if (MODE == 0) {
                        ((bf16*)C)[(size_t)rg * N_out + cg] =
                            __float2bfloat16(acc[mr][nc][rr] + bias[cg]);
                    } else if (MODE == 2) {
                        size_t idx = (size_t)rg * N_out + cg;
                        ((float*)C)[idx] = resid[idx] +
                            gamma[cg] * (acc[mr][nc][rr] + bias[cg]);
                    } else {  // MODE 3
                        if (cg < N_out) {
                            float bv = (cg >= nsplit) ? bias2[cg - nsplit]
                                                      : bias[cg];
                            ((float*)C)[(size_t)rg * N_out + cg] =
                                acc[mr][nc][rr] + bv;
                        }
                    }
                }
            }
        }
    }
}

// ---------------------------------------------------------------------------
// Sampling prep (R12-verified): per-corner records {idx, w}.
// ---------------------------------------------------------------------------
__global__ __launch_bounds__(256) void prep_kernel(
    const float* __restrict__ comb, uint4* __restrict__ pre)
{
    int t  = blockIdx.x * 256 + threadIdx.x;   // (bq*NH + h)*12 + p
    int p  = t % 12;
    int uh = t / 12;
    int h  = uh % NH;
    int bq = uh / NH;
    int q  = bq & (LQ - 1);
    int b  = bq >> 12;

    const float* rowp = comb + (size_t)bq * 432;
    const float* lg = rowp + 288 + h * 12;

    float4 a4 = ((const float4*)lg)[0];
    float4 b4 = ((const float4*)lg)[1];
    float4 c4 = ((const float4*)lg)[2];
    float mx = fmaxf(fmaxf(fmaxf(fmaxf(a4.x, a4.y), fmaxf(a4.z, a4.w)),
                           fmaxf(fmaxf(b4.x, b4.y), fmaxf(b4.z, b4.w))),
                     fmaxf(fmaxf(c4.x, c4.y), fmaxf(c4.z, c4.w)));
    float den = __expf(a4.x - mx) + __expf(a4.y - mx) + __expf(a4.z - mx) +
                __expf(a4.w - mx) + __expf(b4.x - mx) + __expf(b4.y - mx) +
                __expf(b4.z - mx) + __expf(b4.w - mx) + __expf(c4.x - mx) +
                __expf(c4.y - mx) + __expf(c4.z - mx) + __expf(c4.w - mx);
    float lp  = lg[p];
    float awn = __expf(lp - mx) / den;        // normalized attention weight

    int lvl = p >> 2;
    const int wl = (lvl == 0) ? 112 : (lvl == 1 ? 56 : 28);
    const int sl = (lvl == 0) ? 0   : (lvl == 1 ? 12544 : 15680);

    float2 oxy = *(const float2*)(rowp + h * 24 + p * 2);

    float rx = ((q & 63) + 0.5f) * (1.f / 64.f);
    float ry = ((q >> 6) + 0.5f) * (1.f / 64.f);
    float x = rx * wl + oxy.x - 0.5f;
    float y = ry * wl + oxy.y - 0.5f;
    float xf = floorf(x), yf = floorf(y);
    float wx = x - xf, wy = y - yf;
    int x0 = (int)xf, x1 = x0 + 1;
    int y0 = (int)yf, y1 = y0 + 1;
    bool vx0 = (unsigned)x0 < (unsigned)wl, vx1 = (unsigned)x1 < (unsigned)wl;
    bool vy0 = (unsigned)y0 < (unsigned)wl, vy1 = (unsigned)y1 < (unsigned)wl;
    int x0c = min(max(x0, 0), wl - 1), x1c = min(max(x1, 0), wl - 1);
    int y0c = min(max(y0, 0), wl - 1), y1c = min(max(y1, 0), wl - 1);

    int base = b * LIN + sl;
    int yb0 = (base + y0c * wl) * (NH * HD) + h * HD;
    int yb1 = (base + y1c * wl) * (NH * HD) + h * HD;
    int xb0 = x0c * (NH * HD);
    int xb1 = x1c * (NH * HD);

    float wx0 = vx0 ? (1.f - wx) * awn : 0.f;
    float wx1 = vx1 ? wx * awn : 0.f;
    float wy0f = vy0 ? (1.f - wy) : 0.f;
    float wy1f = vy1 ? wy : 0.f;

    uint4 r0 = {(unsigned)(yb0 + xb0), __float_as_uint(wx0 * wy0f),
                (unsigned)(yb0 + xb1), __float_as_uint(wx1 * wy0f)};
    uint4 r1 = {(unsigned)(yb1 + xb0), __float_as_uint(wx0 * wy1f),
                (unsigned)(yb1 + xb1), __float_as_uint(wx1 * wy1f)};
    pre[(size_t)t * 2 + 0] = r0;
    pre[(size_t)t * 2 + 1] = r1;
}

// ---------------------------------------------------------------------------
// Deformable sampling (R12-verified): 3-phase batched loads, per-corner recs.
// ---------------------------------------------------------------------------
__global__ __launch_bounds__(256) void sample_kernel(
    const bf16*  __restrict__ value,
    const uint4* __restrict__ pre,
    bf16*        __restrict__ attn)
{
    __shared__ float red[4][8][64];   // [wave][slot][ch] = 8 KB

    int wv   = threadIdx.x >> 6;
    int wg   = xcd_swz(blockIdx.x, gridDim.x);
    int unit = __builtin_amdgcn_readfirstlane((wg << 2) + wv);
    int lane = threadIdx.x & 63;
    int o   = lane & 7;          // channel octet
    int c8  = lane >> 3;         // corner slot 0..7
    int k   = c8 & 3;            // corner dy*2+dx
    int hi  = (c8 >> 2) & 1;     // which point of the pair
    int h  = unit % NH;
    int bq = unit / NH;

    const uint2* pr = (const uint2*)((const char*)pre
        + (size_t)unit * 384 + hi * 32 + k * 8);

    uint2 rec[6];
    #pragma unroll
    for (int it = 0; it < 6; it++) rec[it] = pr[it * 8];

    const bf16* vb = value + o * 8;
    uint4 v[6];
    #pragma unroll
    for (int it = 0; it < 6; it++)
        v[it] = *(const uint4*)(vb + (int)rec[it].x);

    float acc[8] = {0.f};
    #pragma unroll
    for (int it = 0; it < 6; it++) {
        float w = __uint_as_float(rec[it].y);
        const unsigned* u = (const unsigned*)&v[it];
        #pragma unroll
        for (int j = 0; j < 4; j++) {
            float f0 = __uint_as_float(u[j] << 16);
            float f1 = __uint_as_float(u[j] & 0xFFFF0000u);
            acc[j * 2 + 0] = fmaf(w, f0, acc[j * 2 + 0]);
            acc[j * 2 + 1] = fmaf(w, f1, acc[j * 2 + 1]);
        }
    }

    {
        float* rw = &red[wv][c8][0];
        int base = (o * 8 + c8 * 4) & 63;          // multiple of 4
        *(float4*)&rw[base] = float4{acc[0], acc[1], acc[2], acc[3]};
        *(float4*)&rw[(base + 4) & 63] = float4{acc[4], acc[5], acc[6], acc[7]};
    }
    asm volatile("s_waitcnt lgkmcnt(0)" ::: "memory");
    __builtin_amdgcn_sched_barrier(0);
    float sum = 0.f;
    #pragma unroll
    for (int s = 0; s < 8; s++)
        sum += red[wv][s][(lane + s * 4) & 63];

    attn[(size_t)bq * DM + h * HD + lane] = __float2bfloat16(sum);
}

// ---------------------------------------------------------------------------
extern "C" void kernel_launch(void* const* d_in, const int* in_sizes, int n_in,
                              void* d_out, int out_size, void* d_ws, size_t ws_size,
                              hipStream_t stream)
{
    const float* query  = (const float*)d_in[0];
    const float* feat   = (const float*)d_in[1];
    const float* ln_q_g = (const float*)d_in[2];
    const float* ln_q_b = (const float*)d_in[3];
    const float* ln_f_g = (const float*)d_in[4];
    const float* ln_f_b = (const float*)d_in[5];
    const float* W_off  = (const float*)d_in[6];
    const float* b_off  = (const float*)d_in[7];
    const float* W_attn = (const float*)d_in[8];
    const float* b_attn = (const float*)d_in[9];
    const float* W_val  = (const float*)d_in[10];
    const float* b_val  = (const float*)d_in[11];
    const float* W_out  = (const float*)d_in[12];
    const float* b_out  = (const float*)d_in[13];
    const float* gamma  = (const float*)d_in[14];
    float* out = (float*)d_out;

    char* ws = (char*)d_ws;
    char* od = (char*)d_out;
    const int M_F = BB * LIN;   // 65856
    const int M_Q = BB * LQ;    // 16384

    // ws layout (227,475,456 B proven):
    bf16*  value  = (bf16*)(ws);
    bf16*  f_ln   = (bf16*)(ws + 101154816);
    bf16*  Wt_out = (bf16*)(ws + 101154816);
    // pre lives in the dead f_ln region, after Wt_out (1.2 MB): 75.5 MB fits
    uint4* pre    = (uint4*)(ws + 101154816 + 4194304);
    bf16*  q_ln   = (bf16*)(ws + 202309632);
    bf16*  attn   = (bf16*)(ws + 202309632);

    // d_out as scratch (dead before final GEMM):
    bf16*  Wt_val  = (bf16*)(od);
    bf16*  Wt_comb = (bf16*)(od + 1179648);   // 512 rows x 768 (432-511 zero)
    float* comb    = (float*)(od + 2162688);

    // 1. weight cast/transpose
    cast_transpose<<<dim3(24, 24), 256, 0, stream>>>(W_val, Wt_val, 768);
    cast_transpose<<<dim3(9, 24), 256, 0, stream>>>(W_off, Wt_comb, 288);
    cast_transpose<<<dim3(7, 24), 256, 0, stream>>>(
        W_attn, Wt_comb + (size_t)288 * K_DIM, 144);

    // 2. LayerNorms (wave-per-row; rows are multiples of 4)
    ln_kernel<<<M_F / 4, 256, 0, stream>>>(feat, ln_f_g, ln_f_b, f_ln);
    ln_kernel<<<M_Q / 4, 256, 0, stream>>>(query, ln_q_g, ln_q_b, q_ln);

    // 3. value = f_ln @ W_val + b_val (bf16) — 256x128 pipe
    gemm_pipe<0><<<dim3(6, (M_F + 255) / 256), 512, 0, stream>>>(
        f_ln, Wt_val, b_val, value, nullptr, nullptr, nullptr, M_F, DM, 0);

    // 4. Wt_out into f_ln's (now dead) region
    cast_transpose<<<dim3(24, 24), 256, 0, stream>>>(W_out, Wt_out, 768);

    // 5. comb = q_ln @ [W_off | W_attn] + [b_off | b_attn] (f32, 432 cols;
    //    B padded to 512 rows -> 4 clean bn-blocks, store-guarded)
    gemm_pipe<3><<<dim3(4, M_Q / 256), 512, 0, stream>>>(
        q_ln, Wt_comb, b_off, comb, nullptr, nullptr, b_attn, M_Q, 432, 288);

    // 5.5 per-point sampling precompute (softmax + addressing, once per point)
    prep_kernel<<<(M_Q * NH * 12) / 256, 256, 0, stream>>>(comb, pre);

    // 6. deformable sampling -> attn (bf16)
    sample_kernel<<<(M_Q * NH) / 4, 256, 0, stream>>>(value, pre, attn);

    // 7. out = query + gamma * (attn @ W_out + b_out) — 256x128 pipe
    gemm_pipe<2><<<dim3(6, M_Q / 256), 512, 0, stream>>>(
        attn, Wt_out, b_out, out, query, gamma, nullptr, M_Q, DM, 0);
}

// Round 15
// 646.428 us; speedup vs baseline: 1.0493x; 1.0265x over previous
//
#include <hip/hip_runtime.h>
#include <hip/hip_bf16.h>

typedef __hip_bfloat16 bf16;

// Problem constants
#define BB    4
#define LQ    4096
#define LIN   16464
#define DM    768
#define NH    12
#define HD    64
#define K_DIM 768
// Levels: (112,112),(56,56),(28,28); starts 0,12544,15680; query grid 64x64

typedef __attribute__((ext_vector_type(8))) __bf16 bfrag;
typedef __attribute__((ext_vector_type(4))) float  ffrag;

// ---------------------------------------------------------------------------
// async global->LDS 16B per lane (LDS dest is wave-uniform base + lane*16)
// ---------------------------------------------------------------------------
__device__ __forceinline__ void g2l16(const void* g, void* l) {
    __builtin_amdgcn_global_load_lds(
        (const __attribute__((address_space(1))) void*)g,
        (__attribute__((address_space(3))) void*)l, 16, 0, 0);
}

// bijective XCD-chunk swizzle (m204)
__device__ __forceinline__ int xcd_swz(int orig, int nwg) {
    int xcd = orig & 7, within = orig >> 3;
    int q = nwg >> 3, r = nwg & 7;
    return (xcd < r ? xcd * (q + 1) : r * (q + 1) + (xcd - r) * q) + within;
}

// ---------------------------------------------------------------------------
// Fused LayerNorm for feat AND query (one launch): one wave per row.
// Rows [0, MF) -> feat/f_ln; rows [MF, MF+MQ) -> query/q_ln. Branch is
// wave-uniform (r constant per wave) -> no divergence cost.
// ---------------------------------------------------------------------------
__global__ __launch_bounds__(256) void ln_fused(
    const float* __restrict__ feat,  const float* __restrict__ fg,
    const float* __restrict__ fb,    bf16* __restrict__ fo,
    const float* __restrict__ query, const float* __restrict__ qg,
    const float* __restrict__ qb,    bf16* __restrict__ qo, int MF)
{
    int r = blockIdx.x * 4 + (threadIdx.x >> 6);
    int lane = threadIdx.x & 63;
    const float* x; const float* g; const float* beta; bf16* y;
    if (r < MF) {
        x = feat + (size_t)r * DM; g = fg; beta = fb; y = fo + (size_t)r * DM;
    } else {
        int r2 = r - MF;
        x = query + (size_t)r2 * DM; g = qg; beta = qb; y = qo + (size_t)r2 * DM;
    }
    const float4* xr = (const float4*)x;
    float4 v[3];
    #pragma unroll
    for (int i = 0; i < 3; i++) v[i] = xr[lane + 64 * i];
    float s = 0.f, ss = 0.f;
    #pragma unroll
    for (int i = 0; i < 3; i++) {
        s  += v[i].x + v[i].y + v[i].z + v[i].w;
        ss += v[i].x * v[i].x + v[i].y * v[i].y + v[i].z * v[i].z + v[i].w * v[i].w;
    }
    #pragma unroll
    for (int m = 1; m <= 32; m <<= 1) {
        s  += __shfl_xor(s, m);
        ss += __shfl_xor(ss, m);
    }
    float mean = s * (1.f / DM);
    float inv  = rsqrtf(ss * (1.f / DM) - mean * mean + 1e-6f);
    #pragma unroll
    for (int i = 0; i < 3; i++) {
        float4 gg = ((const float4*)g)[lane + 64 * i];
        float4 bb = ((const float4*)beta)[lane + 64 * i];
        union { bf16 h[4]; uint2 u; } p;
        p.h[0] = __float2bfloat16((v[i].x - mean) * inv * gg.x + bb.x);
        p.h[1] = __float2bfloat16((v[i].y - mean) * inv * gg.y + bb.y);
        p.h[2] = __float2bfloat16((v[i].z - mean) * inv * gg.z + bb.z);
        p.h[3] = __float2bfloat16((v[i].w - mean) * inv * gg.w + bb.w);
        *(uint2*)(y + (lane + 64 * i) * 4) = p.u;
    }
}

// ---------------------------------------------------------------------------
// Cast + transpose weights: W (768 x N f32, row-major) -> Wt (gridX*32 x 768 bf16)
// ---------------------------------------------------------------------------
__global__ __launch_bounds__(256) void cast_transpose(
    const float* __restrict__ W, bf16* __restrict__ Wt, int N)
{
    __shared__ float t[32][33];
    int n0 = blockIdx.x * 32, k0 = blockIdx.y * 32;
    int tx = threadIdx.x & 31, ty = threadIdx.x >> 5;  // ty 0..7
    #pragma unroll
    for (int i = 0; i < 4; i++) {
        int k = k0 + ty + i * 8;
        int n = n0 + tx;
        t[ty + i * 8][tx] = (n < N) ? W[(size_t)k * N + n] : 0.f;
    }
    __syncthreads();
    #pragma unroll
    for (int i = 0; i < 4; i++) {
        int n = n0 + ty + i * 8;
        Wt[(size_t)n * K_DIM + k0 + tx] = __float2bfloat16(t[tx][ty + i * 8]);
    }
}

// ---------------------------------------------------------------------------
// 256x128-tile 8-wave GEMM pipe, R15: per-wave 64x64 (4x4 frags, wave grid
// 4Mx2N). LDS-read ratio (m+n)/(m*n): 8x2 = 0.625 KB/MFMA -> 4x4 = 0.5
// (-20% on the dominant LDS-pipe term; R13's 8x2 pinned at 130us with ~74us
// of LDS traffic). Regs: acc 64 + af 16 + bf 16 + misc ~ 110 <= 128 cap
// (__launch_bounds__(512,4) -> 2 blocks/CU, R13-verified). BK=32, 3-deep
// rotation (72KB), counted vmcnt(6). Swizzle identical (R13: conflicts = 0).
// MODE 0: bf16 (value); MODE 2: f32 resid+gamma*(acc+bias) (out);
// MODE 3: f32 dual-bias split, store guard cg<N_out (comb; B zero-padded).
// ---------------------------------------------------------------------------
template<int MODE>
__global__ __launch_bounds__(512, 4) void gemm_pipe(
    const bf16*  __restrict__ A,
    const bf16*  __restrict__ Bt,
    const float* __restrict__ bias,
    void*        __restrict__ C,
    const float* __restrict__ resid,
    const float* __restrict__ gamma,
    const float* __restrict__ bias2,
    int M, int N_out, int nsplit)
{
    __shared__ __align__(16) char lds[73728];   // 3 x (A 16K + B 8K)

    int tid  = threadIdx.x;
    int lane = tid & 63;
    int wave = tid >> 6;

    int nwg  = gridDim.x * gridDim.y;
    int orig = blockIdx.y * gridDim.x + blockIdx.x;
    int wg   = xcd_swz(orig, nwg);
    int bn = (wg % gridDim.x) * 128;
    int bm = (wg / gridDim.x) * 256;

    int wr = (wave >> 1) * 64;        // rows [wr, +64)
    int wc = (wave & 1) * 64;         // cols [wc, +64)

    int mrow = lane & 15;
    int kqs  = (((lane >> 4) ^ ((mrow >> 1) & 3)) * 8);  // swizzled k-octet

    ffrag acc[4][4] = {};

    // staging: A [256][32] = 16KB (2 chunks/thread), B [128][32] = 8KB (1).
    int rA = tid >> 2;                          // 0..127
    int kb = (((tid & 3) ^ ((rA >> 1) & 3)) * 8);
    int ra0 = min(bm + rA, M - 1), ra1 = min(bm + 128 + rA, M - 1);
    const bf16* gA0 = A  + (size_t)ra0 * K_DIM + kb;
    const bf16* gA1 = A  + (size_t)ra1 * K_DIM + kb;
    const bf16* gB0 = Bt + (size_t)(bn + rA) * K_DIM + kb;   // rows zero-padded

    auto stage = [&](char* buf, int kt) {
        const int ko = kt * 32;
        g2l16(gA0 + ko, buf + tid * 16);
        g2l16(gA1 + ko, buf + tid * 16 + 8192);
        g2l16(gB0 + ko, buf + 16384 + tid * 16);
    };

    char* b0 = lds;
    char* b1 = lds + 24576;
    char* b2 = lds + 49152;
    stage(b0, 0); stage(b1, 1); stage(b2, 2);   // 9 loads in flight

    #pragma unroll
    for (int kt = 0; kt < 24; kt++) {
        if (kt + 2 < 24)      asm volatile("s_waitcnt vmcnt(6)" ::: "memory");
        else if (kt + 1 < 24) asm volatile("s_waitcnt vmcnt(3)" ::: "memory");
        else                  asm volatile("s_waitcnt vmcnt(0)" ::: "memory");
        __builtin_amdgcn_s_barrier();

        const char* Ab = b0 + wr * 64;
        const char* Bb = b0 + 16384 + wc * 64;
        bfrag af[4], bf[4];
        #pragma unroll
        for (int mr = 0; mr < 4; mr++)
            af[mr] = *(const bfrag*)(Ab + (mr * 16 + mrow) * 64 + kqs * 2);
        #pragma unroll
        for (int nc = 0; nc < 4; nc++)
            bf[nc] = *(const bfrag*)(Bb + (nc * 16 + mrow) * 64 + kqs * 2);

        __builtin_amdgcn_s_setprio(1);
        #pragma unroll
        for (int mr = 0; mr < 4; mr++)
            #pragma unroll
            for (int nc = 0; nc < 4; nc++)
                acc[mr][nc] = __builtin_amdgcn_mfma_f32_16x16x32_bf16(
                    af[mr], bf[nc], acc[mr][nc], 0, 0, 0);
        __builtin_amdgcn_s_setprio(0);

        __builtin_amdgcn_s_barrier();       // all waves done reading b0
        if (kt + 3 < 24) stage(b0, kt + 3); // refill freed buffer
        char* tp = b0; b0 = b1; b1 = b2; b2 = tp;
    }

    // epilogue: C/D layout col = lane&15, row = (lane>>4)*4 + reg
    int q4 = (lane >> 4) * 4;
    #pragma unroll
    for (int mr = 0; mr < 4; mr++) {
        #pragma unroll
        for (int rr = 0; rr < 4; rr++) {
            int rg = bm + wr + mr * 16 + q4 + rr;
            if (rg < M) {
                #pragma unroll
                for (int nc = 0; nc < 4; nc++) {
                    int cg = bn + wc + nc * 16 + mrow;
                    if (MODE == 0) {
                        ((bf16*)C)[(size_t)rg * N_out + cg] =
                            __float2bfloat16(acc[mr][nc][rr] + bias[cg]);
                    } else if (MODE == 2) {
                        size_t idx = (size_t)rg * N_out + cg;
                        ((float*)C)[idx] = resid[idx] +
                            gamma[cg] * (acc[mr][nc][rr] + bias[cg]);
                    } else {  // MODE 3
                        if (cg < N_out) {
                            float bv = (cg >= nsplit) ? bias2[cg - nsplit]
                                                      : bias[cg];
                            ((float*)C)[(size_t)rg * N_out + cg] =
                                acc[mr][nc][rr] + bv;
                        }
                    }
                }
            }
        }
    }
}

// ---------------------------------------------------------------------------
// Sampling prep (R12-verified): per-corner records {idx, w}.
// ---------------------------------------------------------------------------
__global__ __launch_bounds__(256) void prep_kernel(
    const float* __restrict__ comb, uint4* __restrict__ pre)
{
    int t  = blockIdx.x * 256 + threadIdx.x;   // (bq*NH + h)*12 + p
    int p  = t % 12;
    int uh = t / 12;
    int h  = uh % NH;
    int bq = uh / NH;
    int q  = bq & (LQ - 1);
    int b  = bq >> 12;

    const float* rowp = comb + (size_t)bq * 432;
    const float* lg = rowp + 288 + h * 12;

    float4 a4 = ((const float4*)lg)[0];
    float4 b4 = ((const float4*)lg)[1];
    float4 c4 = ((const float4*)lg)[2];
    float mx = fmaxf(fmaxf(fmaxf(fmaxf(a4.x, a4.y), fmaxf(a4.z, a4.w)),
                           fmaxf(fmaxf(b4.x, b4.y), fmaxf(b4.z, b4.w))),
                     fmaxf(fmaxf(c4.x, c4.y), fmaxf(c4.z, c4.w)));
    float den = __expf(a4.x - mx) + __expf(a4.y - mx) + __expf(a4.z - mx) +
                __expf(a4.w - mx) + __expf(b4.x - mx) + __expf(b4.y - mx) +
                __expf(b4.z - mx) + __expf(b4.w - mx) + __expf(c4.x - mx) +
                __expf(c4.y - mx) + __expf(c4.z - mx) + __expf(c4.w - mx);
    float lp  = lg[p];
    float awn = __expf(lp - mx) / den;        // normalized attention weight

    int lvl = p >> 2;
    const int wl = (lvl == 0) ? 112 : (lvl == 1 ? 56 : 28);
    const int sl = (lvl == 0) ? 0   : (lvl == 1 ? 12544 : 15680);

    float2 oxy = *(const float2*)(rowp + h * 24 + p * 2);

    float rx = ((q & 63) + 0.5f) * (1.f / 64.f);
    float ry = ((q >> 6) + 0.5f) * (1.f / 64.f);
    float x = rx * wl + oxy.x - 0.5f;
    float y = ry * wl + oxy.y - 0.5f;
    float xf = floorf(x), yf = floorf(y);
    float wx = x - xf, wy = y - yf;
    int x0 = (int)xf, x1 = x0 + 1;
    int y0 = (int)yf, y1 = y0 + 1;
    bool vx0 = (unsigned)x0 < (unsigned)wl, vx1 = (unsigned)x1 < (unsigned)wl;
    bool vy0 = (unsigned)y0 < (unsigned)wl, vy1 = (unsigned)y1 < (unsigned)wl;
    int x0c = min(max(x0, 0), wl - 1), x1c = min(max(x1, 0), wl - 1);
    int y0c = min(max(y0, 0), wl - 1), y1c = min(max(y1, 0), wl - 1);

    int base = b * LIN + sl;
    int yb0 = (base + y0c * wl) * (NH * HD) + h * HD;
    int yb1 = (base + y1c * wl) * (NH * HD) + h * HD;
    int xb0 = x0c * (NH * HD);
    int xb1 = x1c * (NH * HD);

    float wx0 = vx0 ? (1.f - wx) * awn : 0.f;
    float wx1 = vx1 ? wx * awn : 0.f;
    float wy0f = vy0 ? (1.f - wy) : 0.f;
    float wy1f = vy1 ? wy : 0.f;

    uint4 r0 = {(unsigned)(yb0 + xb0), __float_as_uint(wx0 * wy0f),
                (unsigned)(yb0 + xb1), __float_as_uint(wx1 * wy0f)};
    uint4 r1 = {(unsigned)(yb1 + xb0), __float_as_uint(wx0 * wy1f),
                (unsigned)(yb1 + xb1), __float_as_uint(wx1 * wy1f)};
    pre[(size_t)t * 2 + 0] = r0;
    pre[(size_t)t * 2 + 1] = r1;
}

// ---------------------------------------------------------------------------
// Deformable sampling (R12-verified): 3-phase batched loads, per-corner recs.
// ---------------------------------------------------------------------------
__global__ __launch_bounds__(256) void sample_kernel(
    const bf16*  __restrict__ value,
    const uint4* __restrict__ pre,
    bf16*        __restrict__ attn)
{
    __shared__ float red[4][8][64];   // [wave][slot][ch] = 8 KB

    int wv   = threadIdx.x >> 6;
    int wg   = xcd_swz(blockIdx.x, gridDim.x);
    int unit = __builtin_amdgcn_readfirstlane((wg << 2) + wv);
    int lane = threadIdx.x & 63;
    int o   = lane & 7;          // channel octet
    int c8  = lane >> 3;         // corner slot 0..7
    int k   = c8 & 3;            // corner dy*2+dx
    int hi  = (c8 >> 2) & 1;     // which point of the pair
    int h  = unit % NH;
    int bq = unit / NH;

    const uint2* pr = (const uint2*)((const char*)pre
        + (size_t)unit * 384 + hi * 32 + k * 8);

    uint2 rec[6];
    #pragma unroll
    for (int it = 0; it < 6; it++) rec[it] = pr[it * 8];

    const bf16* vb = value + o * 8;
    uint4 v[6];
    #pragma unroll
    for (int it = 0; it < 6; it++)
        v[it] = *(const uint4*)(vb + (int)rec[it].x);

    float acc[8] = {0.f};
    #pragma unroll
    for (int it = 0; it < 6; it++) {
        float w = __uint_as_float(rec[it].y);
        const unsigned* u = (const unsigned*)&v[it];
        #pragma unroll
        for (int j = 0; j < 4; j++) {
            float f0 = __uint_as_float(u[j] << 16);
            float f1 = __uint_as_float(u[j] & 0xFFFF0000u);
            acc[j * 2 + 0] = fmaf(w, f0, acc[j * 2 + 0]);
            acc[j * 2 + 1] = fmaf(w, f1, acc[j * 2 + 1]);
        }
    }

    {
        float* rw = &red[wv][c8][0];
        int base = (o * 8 + c8 * 4) & 63;          // multiple of 4
        *(float4*)&rw[base] = float4{acc[0], acc[1], acc[2], acc[3]};
        *(float4*)&rw[(base + 4) & 63] = float4{acc[4], acc[5], acc[6], acc[7]};
    }
    asm volatile("s_waitcnt lgkmcnt(0)" ::: "memory");
    __builtin_amdgcn_sched_barrier(0);
    float sum = 0.f;
    #pragma unroll
    for (int s = 0; s < 8; s++)
        sum += red[wv][s][(lane + s * 4) & 63];

    attn[(size_t)bq * DM + h * HD + lane] = __float2bfloat16(sum);
}

// ---------------------------------------------------------------------------
extern "C" void kernel_launch(void* const* d_in, const int* in_sizes, int n_in,
                              void* d_out, int out_size, void* d_ws, size_t ws_size,
                              hipStream_t stream)
{
    const float* query  = (const float*)d_in[0];
    const float* feat   = (const float*)d_in[1];
    const float* ln_q_g = (const float*)d_in[2];
    const float* ln_q_b = (const float*)d_in[3];
    const float* ln_f_g = (const float*)d_in[4];
    const float* ln_f_b = (const float*)d_in[5];
    const float* W_off  = (const float*)d_in[6];
    const float* b_off  = (const float*)d_in[7];
    const float* W_attn = (const float*)d_in[8];
    const float* b_attn = (const float*)d_in[9];
    const float* W_val  = (const float*)d_in[10];
    const float* b_val  = (const float*)d_in[11];
    const float* W_out  = (const float*)d_in[12];
    const float* b_out  = (const float*)d_in[13];
    const float* gamma  = (const float*)d_in[14];
    float* out = (float*)d_out;

    char* ws = (char*)d_ws;
    char* od = (char*)d_out;
    const int M_F = BB * LIN;   // 65856
    const int M_Q = BB * LQ;    // 16384

    // ws layout (227,475,456 B proven):
    bf16*  value  = (bf16*)(ws);
    bf16*  f_ln   = (bf16*)(ws + 101154816);
    bf16*  Wt_out = (bf16*)(ws + 101154816);
    // pre lives in the dead f_ln region, after Wt_out (1.2 MB): 75.5 MB fits
    uint4* pre    = (uint4*)(ws + 101154816 + 4194304);
    bf16*  q_ln   = (bf16*)(ws + 202309632);
    bf16*  attn   = (bf16*)(ws + 202309632);

    // d_out as scratch (dead before final GEMM):
    bf16*  Wt_val  = (bf16*)(od);
    bf16*  Wt_comb = (bf16*)(od + 1179648);   // 512 rows x 768 (432-511 zero)
    float* comb    = (float*)(od + 2162688);

    // 1. weight cast/transpose
    cast_transpose<<<dim3(24, 24), 256, 0, stream>>>(W_val, Wt_val, 768);
    cast_transpose<<<dim3(9, 24), 256, 0, stream>>>(W_off, Wt_comb, 288);
    cast_transpose<<<dim3(7, 24), 256, 0, stream>>>(
        W_attn, Wt_comb + (size_t)288 * K_DIM, 144);

    // 2. Fused LayerNorms (feat rows then query rows; wave-uniform branch)
    ln_fused<<<(M_F + M_Q) / 4, 256, 0, stream>>>(
        feat, ln_f_g, ln_f_b, f_ln, query, ln_q_g, ln_q_b, q_ln, M_F);

    // 3. value = f_ln @ W_val + b_val (bf16) — 256x128 pipe, 4x4 wave tile
    gemm_pipe<0><<<dim3(6, (M_F + 255) / 256), 512, 0, stream>>>(
        f_ln, Wt_val, b_val, value, nullptr, nullptr, nullptr, M_F, DM, 0);

    // 4. Wt_out into f_ln's (now dead) region
    cast_transpose<<<dim3(24, 24), 256, 0, stream>>>(W_out, Wt_out, 768);

    // 5. comb = q_ln @ [W_off | W_attn] + [b_off | b_attn] (f32, 432 cols)
    gemm_pipe<3><<<dim3(4, M_Q / 256), 512, 0, stream>>>(
        q_ln, Wt_comb, b_off, comb, nullptr, nullptr, b_attn, M_Q, 432, 288);

    // 5.5 per-point sampling precompute (softmax + addressing, once per point)
    prep_kernel<<<(M_Q * NH * 12) / 256, 256, 0, stream>>>(comb, pre);

    // 6. deformable sampling -> attn (bf16)
    sample_kernel<<<(M_Q * NH) / 4, 256, 0, stream>>>(value, pre, attn);

    // 7. out = query + gamma * (attn @ W_out + b_out) — 256x128 pipe
    gemm_pipe<2><<<dim3(6, M_Q / 256), 512, 0, stream>>>(
        attn, Wt_out, b_out, out, query, gamma, nullptr, M_Q, DM, 0);
}